// Round 16
// baseline (36.517 us; speedup 1.0000x reference)
//
#include <hip/hip_runtime.h>
#include <hip/hip_bf16.h>

#define EPS 1e-5f

typedef __attribute__((ext_vector_type(8))) short bf16x8;
typedef __attribute__((ext_vector_type(4))) float f32x4;
typedef __attribute__((ext_vector_type(4))) unsigned int u32x4;
typedef unsigned short ushort_t;
#define MFMA16(a, b, c) __builtin_amdgcn_mfma_f32_16x16x32_bf16(a, b, c, 0, 0, 0)

// ---- ws layout (half-index offsets unchanged from r15) ----
// f32  [144..367]  consts: a1[16] c1[16] a2[32] c2[32] a3[64] c3[64]
// bf16 half-index 1024:   W2F  2mt*5ks*64lane*8  = 5120
// bf16 half-index 6144:   W3F  4mt*9ks*64*8      = 18432
// bf16 half-index 24576:  WFC1F 8mt*20ks*64*8    = 81920  (k'-regions)
// bf16 half-index 106496: W1F  2(hi/lo)*64lane*8 = 1024
#define CST_OFF  144
#define W2F_H    1024
#define W3F_H    6144
#define WFC1F_H  24576
#define W1F_H    106496
// prep jobs: [0,224) consts | [224,5344) W2F | [5344,23776) W3F |
//            [23776,24800) W1F | [24800,32992) WFC1F zero-pads |
//            [32992,106720) WFC1F inverted (coalesced wfc1 reads)
#define PREP_ITEMS 106720

__device__ __forceinline__ unsigned short f2bf(float f) {
    unsigned int u = __builtin_bit_cast(unsigned int, f);
    return (unsigned short)((u + 0x7fffu + ((u >> 16) & 1u)) >> 16);
}

__global__ __launch_bounds__(256) void prep_kernel(
    const int* __restrict__ y_int,
    const float* __restrict__ w2, const float* __restrict__ w3,
    const float* __restrict__ wfc1,
    const float* __restrict__ bias1,
    const float* __restrict__ g1, const float* __restrict__ b1,
    const float* __restrict__ m1, const float* __restrict__ v1,
    const float* __restrict__ g2, const float* __restrict__ b2,
    const float* __restrict__ m2, const float* __restrict__ v2,
    const float* __restrict__ bias2,
    const float* __restrict__ g3, const float* __restrict__ b3,
    const float* __restrict__ m3, const float* __restrict__ v3,
    const float* __restrict__ bias3,
    float* __restrict__ ws)
{
    unsigned short* wsh = (unsigned short*)ws;
    int i = blockIdx.x * 256 + threadIdx.x;
    if (i < 224) {
        int idx = i;
        float v;
        if (idx < 16) { int c = idx;
            v = g1[c] * rsqrtf(v1[c] + EPS) * 1e-4f;
        } else if (idx < 32) { int c = idx - 16;
            float inv = g1[c] * rsqrtf(v1[c] + EPS);
            v = bias1[c] * inv + b1[c] - m1[c] * inv;
        } else if (idx < 64) { int c = idx - 32;
            v = g2[c] * rsqrtf(v2[c] + EPS);
        } else if (idx < 96) { int c = idx - 64;
            float inv = g2[c] * rsqrtf(v2[c] + EPS);
            v = bias2[c] * inv + b2[c] - m2[c] * inv;
        } else if (idx < 160) { int c = idx - 96;
            v = g3[c] * rsqrtf(v3[c] + EPS);
        } else { int c = idx - 160;
            float inv = g3[c] * rsqrtf(v3[c] + EPS);
            v = bias3[c] * inv + b3[c] - m3[c] * inv;
        }
        ws[CST_OFF + idx] = v;
    } else if (i < 5344) {
        int e = i - 224;
        int m = e / 2560, r = e % 2560, s = r >> 9, l = (r >> 3) & 63, j = e & 7;
        int kl  = ((l >> 4) << 3) + j;
        int tap = 2 * s + (kl >> 4), ci = kl & 15;
        int ch  = m * 16 + (l & 15);
        float v = (tap < 9) ? w2[ch * 144 + ci * 9 + tap] : 0.f;
        wsh[W2F_H + e] = f2bf(v);
    } else if (i < 23776) {
        int e3 = i - 5344;
        int mt = e3 / 4608, r = e3 % 4608, ks = r >> 9, l = (r >> 3) & 63, j = e3 & 7;
        int ch = mt * 16 + (l & 15), ci = ((l >> 4) << 3) + j;
        wsh[W3F_H + e3] = f2bf(w3[ch * 288 + ci * 9 + ks]);
    } else if (i < 24800) {
        int e4 = i - 23776;                          // [0,1024) conv1 frags
        int half = e4 >> 9, l = (e4 >> 3) & 63, j = e4 & 7;
        int g = l >> 4, ch = l & 15;
        float w = 0.f;
        if (g < 3 && !(j & 1) && (j >> 1) < 3)
            w = (float)y_int[ch * 9 + g * 3 + (j >> 1)];
        unsigned short hib = f2bf(w);
        if (half == 0) {
            wsh[W1F_H + e4] = hib;
        } else {
            float hif = __builtin_bit_cast(float, (unsigned int)hib << 16);
            wsh[W1F_H + e4] = f2bf(w - hif);         // exact residual
        }
    } else if (i < 32992) {
        int z = i - 24800;                           // WFC1F zero-pads (lk>=144)
        int mt = z >> 10, r = z & 1023;
        int w = r >> 8, r2 = r & 255;
        int lk = 144 + (r2 >> 4), ch16 = r2 & 15;
        int kp = w * 160 + lk;
        int ks = kp >> 5, kl = kp & 31;
        int l = (kl >> 3) * 16 + ch16, j = kl & 7;
        wsh[WFC1F_H + ((mt * 20 + ks) * 64 + l) * 8 + j] = 0;
    } else if (i < PREP_ITEMS) {
        int s = i - 32992;                           // coalesced read wfc1[s]
        float v = wfc1[s];
        int ch = s / 576, rr = s % 576;
        int ci = rr / 9, pos = rr % 9;
        int w = ci >> 4, lk = (ci & 15) * 9 + pos;
        int kp = w * 160 + lk;
        int ks = kp >> 5, kl = kp & 31;
        int l = (kl >> 3) * 16 + (ch & 15), j = kl & 7;
        int mt = ch >> 4;
        wsh[WFC1F_H + ((mt * 20 + ks) * 64 + l) * 8 + j] = f2bf(v);
    }
}

// 1 image per block (256 thr, 4 waves), 1024 blocks, FOUR barriers.
// r15 structure; A3 fragment loads hoisted above conv2 (latency hides under
// phase C, drained by its end-of-phase vmcnt before bar 3).
__global__ __launch_bounds__(256, 4) void fused_cnn(
    const int* __restrict__ x_img,
    const float* __restrict__ ws,
    const float* __restrict__ bfc1,
    const float* __restrict__ wfc2, const float* __restrict__ bfc2,
    float* __restrict__ out)
{
    const int tid  = threadIdx.x;
    const int lane = tid & 63;
    const int wv   = __builtin_amdgcn_readfirstlane(tid >> 6);  // 0..3
    const int img  = blockIdx.x;
    const unsigned short* wsh = (const unsigned short*)ws;

    __shared__ __align__(16) char         s_f1[8192];
    __shared__ __align__(16) char         s_f2[5184];
    __shared__ __align__(16) unsigned int s_px[1200];   // [30 rows][40 dwords]
    ushort_t* FLAT = (ushort_t*)s_f1;             // 640 bf16 (F1 dead after conv2)
    float*    Hp   = (float*)(s_f1 + 1536);       // [4][128] f32

    // ---- phase A: stage pixels (dup-bf16 dwords) + zero borders ----
    const int* xp = x_img + img * 784;
    for (int i = tid; i < 784; i += 256) {
        int r = i / 28, c = i - r * 28;
        float f = (float)xp[i];
        unsigned int b = __builtin_bit_cast(unsigned int, f) >> 16;
        s_px[(r + 1) * 40 + c + 1] = b | (b << 16);
    }
    {
        uint4 z = make_uint4(0u, 0u, 0u, 0u);
        if (tid < 28) {                    // PX side borders, row tid+1
            unsigned int* row = s_px + (tid + 1) * 40;
            row[0] = 0u;
            #pragma unroll
            for (int c = 29; c < 40; c++) row[c] = 0u;
        } else if (tid < 48) {             // PX rows 0, 29
            int j = tid - 28;
            int row = (j < 10) ? 0 : 29, ch = (j < 10) ? j : j - 10;
            *(uint4*)((char*)s_px + row * 160 + ch * 16) = z;
        } else if (tid < 168) {            // F1 borders
            int zz = tid - 48;
            int c0 = zz / 60, b = zz % 60, pos;
            if (b < 16)      pos = b;
            else if (b < 32) pos = 240 + (b - 16);
            else if (b < 46) pos = (b - 31) * 16;
            else             pos = (b - 45) * 16 + 15;
            *(uint4*)(s_f1 + c0 * 4096 + pos * 16) = z;
        } else {                           // F2 borders
            int i0 = tid - 168;
            #pragma unroll
            for (int rep = 0; rep < 2; rep++) {
                int i2 = i0 + rep * 88;
                if (i2 < 128) {
                    int q = i2 >> 5, b = i2 & 31, pos;
                    if (b < 9)       pos = b;
                    else if (b < 18) pos = 72 + (b - 9);
                    else if (b < 25) pos = (b - 17) * 9;
                    else             pos = (b - 24) * 9 + 8;
                    *(uint4*)(s_f2 + q * 1296 + pos * 16) = z;
                }
            }
        }
    }
    __syncthreads();   // bar 1: PX + borders ready

    // ---- phase B: conv1 via MFMA (hi/lo exact) -> F1 ----
    {
        bf16x8 A1H = *(const bf16x8*)(const void*)(wsh + W1F_H + lane * 8);
        bf16x8 A1L = *(const bf16x8*)(const void*)(wsh + W1F_H + (64 + lane) * 8);
        const int n = lane & 15, g = lane >> 4;
        const int gp = (g < 2) ? g : 2;
        float a1v[4], c1v[4];
        #pragma unroll
        for (int r = 0; r < 4; r++) {
            int ch = g * 4 + r;
            a1v[r] = ws[CST_OFF + ch];
            c1v[r] = ws[CST_OFF + 16 + ch];
        }
        for (int p1 = wv; p1 < 14; p1 += 4) {
            const unsigned int* rb = s_px + (2 * p1 + gp) * 40 + n;
            #pragma unroll
            for (int xt = 0; xt < 2; xt++) {
                const unsigned int* r0 = rb + xt * 16;
                u32x4 t0 = {r0[0], r0[1], r0[2], r0[3]};
                u32x4 t1 = {r0[40], r0[41], r0[42], r0[43]};
                bf16x8 B0 = __builtin_bit_cast(bf16x8, t0);
                bf16x8 B1 = __builtin_bit_cast(bf16x8, t1);
                f32x4 aA = {0.f, 0.f, 0.f, 0.f}, aB = {0.f, 0.f, 0.f, 0.f};
                aA = MFMA16(A1L, B0, aA); aA = MFMA16(A1H, B0, aA);
                aB = MFMA16(A1L, B1, aB); aB = MFMA16(A1H, B1, aB);
                float hp[4];
                #pragma unroll
                for (int r = 0; r < 4; r++) {
                    float vp = fmaxf(aA[r], aB[r]);
                    hp[r] = fmaxf(vp, __shfl_xor(vp, 1));
                }
                if (!(n & 1) && (xt == 0 || n < 12)) {
                    int xpo = xt * 8 + (n >> 1);
                    int pos = (p1 + 1) * 16 + (xpo + 1);
                    int ch0 = g * 4;
                    unsigned int lo = (unsigned int)f2bf(fmaxf(hp[0] * a1v[0] + c1v[0], 0.f)) |
                                      ((unsigned int)f2bf(fmaxf(hp[1] * a1v[1] + c1v[1], 0.f)) << 16);
                    unsigned int hi = (unsigned int)f2bf(fmaxf(hp[2] * a1v[2] + c1v[2], 0.f)) |
                                      ((unsigned int)f2bf(fmaxf(hp[3] * a1v[3] + c1v[3], 0.f)) << 16);
                    *(uint2*)(s_f1 + (ch0 >> 3) * 4096 + pos * 16 + (ch0 & 7) * 2) = make_uint2(lo, hi);
                }
            }
        }
    }
    __syncthreads();   // bar 2: F1 ready

    // ---- A3 fragment loads issued EARLY (hide under conv2) ----
    bf16x8 A3[9];
    {
        const int mt = wv;
        #pragma unroll
        for (int ks = 0; ks < 9; ks++)
            A3[ks] = *(const bf16x8*)(const void*)(wsh + W3F_H + ((mt * 9 + ks) * 64 + lane) * 8);
    }

    // ---- phase C: conv2 via MFMA, rows p in {wv, wv+4} ----
    {
        const int x = lane & 15, g = lane >> 4;
        const int tapb = g >> 1, c0 = g & 1;
        bf16x8 A2[2][5];
        #pragma unroll
        for (int m = 0; m < 2; m++)
            #pragma unroll
            for (int s = 0; s < 5; s++)
                A2[m][s] = *(const bf16x8*)(const void*)(wsh + W2F_H + ((m * 5 + s) * 64 + lane) * 8);
        int voff[5];
        #pragma unroll
        for (int s = 0; s < 5; s++) {
            int tap = 2 * s + tapb;
            int dy = (tap < 9) ? tap / 3 : 0, dx = (tap < 9) ? tap % 3 : 0;
            voff[s] = c0 * 4096 + (dy * 16 + x + dx) * 16;
        }
        float a2v[2][4], c2v[2][4];
        #pragma unroll
        for (int m = 0; m < 2; m++)
            #pragma unroll
            for (int r = 0; r < 4; r++) {
                int ch = m * 16 + g * 4 + r;
                a2v[m][r] = ws[CST_OFF + 32 + ch];
                c2v[m][r] = ws[CST_OFF + 64 + ch];
            }
        for (int p = wv; p < 7; p += 4) {
            const char* bp = s_f1 + p * 512;
            bf16x8 B0[5], B1[5];
            #pragma unroll
            for (int s = 0; s < 5; s++) {
                B0[s] = *(const bf16x8*)(const void*)(bp + voff[s]);
                B1[s] = *(const bf16x8*)(const void*)(bp + 256 + voff[s]);
            }
            #pragma unroll
            for (int m = 0; m < 2; m++) {
                f32x4 a0 = {0.f, 0.f, 0.f, 0.f}, a1 = {0.f, 0.f, 0.f, 0.f};
                #pragma unroll
                for (int s = 0; s < 5; s++) {
                    a0 = MFMA16(A2[m][s], B0[s], a0);
                    a1 = MFMA16(A2[m][s], B1[s], a1);
                }
                float hp[4];
                #pragma unroll
                for (int r = 0; r < 4; r++) {
                    float vp = fmaxf(a0[r], a1[r]);
                    hp[r] = fmaxf(vp, __shfl_xor(vp, 1));
                }
                if (!(x & 1) && x < 14) {
                    int xp2 = x >> 1;
                    int pp  = (p + 1) * 9 + xp2 + 1;
                    int ch0 = m * 16 + g * 4;
                    unsigned int lo = (unsigned int)f2bf(fmaxf(hp[0] * a2v[m][0] + c2v[m][0], 0.f)) |
                                      ((unsigned int)f2bf(fmaxf(hp[1] * a2v[m][1] + c2v[m][1], 0.f)) << 16);
                    unsigned int hi = (unsigned int)f2bf(fmaxf(hp[2] * a2v[m][2] + c2v[m][2], 0.f)) |
                                      ((unsigned int)f2bf(fmaxf(hp[3] * a2v[m][3] + c2v[m][3], 0.f)) << 16);
                    *(uint2*)(s_f2 + (ch0 >> 3) * 1296 + pp * 16 + (ch0 & 7) * 2) = make_uint2(lo, hi);
                }
            }
        }
    }
    __syncthreads();   // bar 3: F2 ready (F1 dead -> FLAT/Hp scratch)

    // ---- phase D: conv3 (mt = wv, A3 already in regs) -> FLAT -> FC1 partial ----
    {
        const int x8 = lane & 7, ry = (lane >> 3) & 1, qg = lane >> 4;
        int voff3[9];
        #pragma unroll
        for (int ks = 0; ks < 9; ks++) {
            int dy = ks / 3, dx = ks % 3;
            voff3[ks] = qg * 1296 + ((ry + dy) * 9 + x8 + dx) * 16;
        }
        float a3v[4], c3v[4];
        #pragma unroll
        for (int r = 0; r < 4; r++) {
            int ch = wv * 16 + qg * 4 + r;
            a3v[r] = ws[CST_OFF + 96 + ch];
            c3v[r] = ws[CST_OFF + 160 + ch];
        }
        if (lane < 16) FLAT[wv * 160 + 144 + lane] = 0;
        #pragma unroll
        for (int t = 0; t < 3; t++) {
            bf16x8 bb[9];
            #pragma unroll
            for (int ks = 0; ks < 9; ks++)
                bb[ks] = *(const bf16x8*)(const void*)(s_f2 + t * 288 + voff3[ks]);
            f32x4 acc = {0.f, 0.f, 0.f, 0.f};
            #pragma unroll
            for (int ks = 0; ks < 9; ks++)
                acc = MFMA16(A3[ks], bb[ks], acc);
            float hp[4];
            #pragma unroll
            for (int r = 0; r < 4; r++) {
                float vp = fmaxf(acc[r], __shfl_xor(acc[r], 8));
                hp[r] = fmaxf(vp, __shfl_xor(vp, 1));
            }
            if (ry == 0 && !(x8 & 1) && x8 < 6) {
                int xp3 = x8 >> 1;
                #pragma unroll
                for (int r = 0; r < 4; r++) {
                    float v = fmaxf(hp[r] * a3v[r] + c3v[r], 0.f);
                    FLAT[wv * 160 + (qg * 4 + r) * 9 + t * 3 + xp3] = f2bf(v);
                }
            }
        }

        // FC1 partial: own k'-slices ks = 5wv..5wv+4, all 8 mt (B hoisted)
        const int g = lane >> 4;
        bf16x8 BV[5];
        #pragma unroll
        for (int ksl = 0; ksl < 5; ksl++)
            BV[ksl] = *(const bf16x8*)(const void*)(FLAT + (wv * 5 + ksl) * 32 + g * 8);
        #pragma unroll
        for (int mtf = 0; mtf < 8; mtf++) {
            f32x4 acc = {0.f, 0.f, 0.f, 0.f};
            #pragma unroll
            for (int ksl = 0; ksl < 5; ksl++) {
                int ks = wv * 5 + ksl;
                bf16x8 a = *(const bf16x8*)(const void*)(wsh + WFC1F_H + ((mtf * 20 + ks) * 64 + lane) * 8);
                acc = MFMA16(a, BV[ksl], acc);
            }
            if ((lane & 15) == 0) {
                int ch0 = mtf * 16 + g * 4;
                #pragma unroll
                for (int r = 0; r < 4; r++)
                    Hp[wv * 128 + ch0 + r] = acc[r];
            }
        }
    }
    __syncthreads();   // bar 4: Hp ready

    // ---- phase E: FC2, combine 4 partials ----
    if (tid < 160) {
        int o = tid / 16, l = tid & 15;
        float a = 0.f;
        #pragma unroll
        for (int k = l; k < 128; k += 16) {
            float h = Hp[k] + Hp[128 + k] + Hp[256 + k] + Hp[384 + k] + bfc1[k];
            h = fmaxf(h, 0.f);
            a += h * wfc2[o * 128 + k];
        }
        a += __shfl_xor(a, 8);
        a += __shfl_xor(a, 4);
        a += __shfl_xor(a, 2);
        a += __shfl_xor(a, 1);
        if (l == 0) out[img * 10 + o] = a + bfc2[o];
    }
}

extern "C" void kernel_launch(void* const* d_in, const int* in_sizes, int n_in,
                              void* d_out, int out_size, void* d_ws, size_t ws_size,
                              hipStream_t stream) {
    float* ws = (float*)d_ws;
    prep_kernel<<<(PREP_ITEMS + 255) / 256, 256, 0, stream>>>(
        (const int*)d_in[1],                        // y_int
        (const float*)d_in[15],                     // w2
        (const float*)d_in[17],                     // w3
        (const float*)d_in[19],                     // w_fc1
        (const float*)d_in[2],                      // bias1
        (const float*)d_in[3], (const float*)d_in[4], (const float*)d_in[5], (const float*)d_in[6],
        (const float*)d_in[7], (const float*)d_in[8], (const float*)d_in[9], (const float*)d_in[10],
        (const float*)d_in[16],                     // bias2
        (const float*)d_in[11], (const float*)d_in[12], (const float*)d_in[13], (const float*)d_in[14],
        (const float*)d_in[18],                     // bias3
        ws);
    fused_cnn<<<1024, 256, 0, stream>>>(
        (const int*)d_in[0],                        // x_img
        ws,
        (const float*)d_in[20],                     // b_fc1
        (const float*)d_in[21], (const float*)d_in[22],  // w_fc2, b_fc2
        (float*)d_out);
}

// Round 17
// 26.543 us; speedup vs baseline: 1.3758x; 1.3758x over previous
//
#include <hip/hip_runtime.h>
#include <hip/hip_bf16.h>

#define EPS 1e-5f

typedef __attribute__((ext_vector_type(8))) short bf16x8;
typedef __attribute__((ext_vector_type(4))) float f32x4;
typedef __attribute__((ext_vector_type(4))) unsigned int u32x4;
typedef unsigned short ushort_t;
#define MFMA16(a, b, c) __builtin_amdgcn_mfma_f32_16x16x32_bf16(a, b, c, 0, 0, 0)

// ---- ws layout ----
// f32  [0..143]    YT (legacy, unused)
// f32  [144..367]  consts: a1[16] c1[16] a2[32] c2[32] a3[64] c3[64]
// bf16 half-index 1024:   W2F  2mt*5ks*64lane*8  = 5120
// bf16 half-index 6144:   W3F  4mt*9ks*64*8      = 18432
// bf16 half-index 24576:  WFC1F 8mt*20ks*64*8    = 81920  (k'-regions, r12)
// bf16 half-index 106496: W1F  2(hi/lo)*64lane*8 = 1024   (conv1 MFMA frags)
//   W1F k-slot (g=l>>4, j): tap (dy=g, dx=j>>1) at even j, g<3; else 0.
#define CST_OFF  144
#define W2F_H    1024
#define W3F_H    6144
#define WFC1F_H  24576
#define W1F_H    106496
#define PREP_ITEMS (368 + 5120 + 18432 + 81920 + 1024)

__device__ __forceinline__ unsigned short f2bf(float f) {
    unsigned int u = __builtin_bit_cast(unsigned int, f);
    return (unsigned short)((u + 0x7fffu + ((u >> 16) & 1u)) >> 16);
}

__global__ __launch_bounds__(256) void prep_kernel(
    const int* __restrict__ y_int,
    const float* __restrict__ w2, const float* __restrict__ w3,
    const float* __restrict__ wfc1,
    const float* __restrict__ bias1,
    const float* __restrict__ g1, const float* __restrict__ b1,
    const float* __restrict__ m1, const float* __restrict__ v1,
    const float* __restrict__ g2, const float* __restrict__ b2,
    const float* __restrict__ m2, const float* __restrict__ v2,
    const float* __restrict__ bias2,
    const float* __restrict__ g3, const float* __restrict__ b3,
    const float* __restrict__ m3, const float* __restrict__ v3,
    const float* __restrict__ bias3,
    float* __restrict__ ws)
{
    unsigned short* wsh = (unsigned short*)ws;
    int i = blockIdx.x * 256 + threadIdx.x;
    if (i < 144) {
        int k = i >> 4, c = i & 15;
        ws[i] = (float)y_int[c * 9 + k];
    } else if (i < 368) {
        int idx = i - 144;
        if (idx < 16) { int c = idx;
            ws[CST_OFF + idx] = g1[c] * rsqrtf(v1[c] + EPS) * 1e-4f;
        } else if (idx < 32) { int c = idx - 16;
            float inv = g1[c] * rsqrtf(v1[c] + EPS);
            ws[CST_OFF + idx] = bias1[c] * inv + b1[c] - m1[c] * inv;
        } else if (idx < 64) { int c = idx - 32;
            ws[CST_OFF + idx] = g2[c] * rsqrtf(v2[c] + EPS);
        } else if (idx < 96) { int c = idx - 64;
            float inv = g2[c] * rsqrtf(v2[c] + EPS);
            ws[CST_OFF + idx] = bias2[c] * inv + b2[c] - m2[c] * inv;
        } else if (idx < 160) { int c = idx - 96;
            ws[CST_OFF + idx] = g3[c] * rsqrtf(v3[c] + EPS);
        } else { int c = idx - 160;
            float inv = g3[c] * rsqrtf(v3[c] + EPS);
            ws[CST_OFF + idx] = bias3[c] * inv + b3[c] - m3[c] * inv;
        }
    } else {
        int e = i - 368;
        if (e < 5120) {
            int m = e / 2560, r = e % 2560, s = r >> 9, l = (r >> 3) & 63, j = e & 7;
            int kl  = ((l >> 4) << 3) + j;
            int tap = 2 * s + (kl >> 4), ci = kl & 15;
            int ch  = m * 16 + (l & 15);
            float v = (tap < 9) ? w2[ch * 144 + ci * 9 + tap] : 0.f;
            wsh[W2F_H + e] = f2bf(v);
        } else if (e < 5120 + 18432) {
            int e3 = e - 5120;
            int mt = e3 / 4608, r = e3 % 4608, ks = r >> 9, l = (r >> 3) & 63, j = e3 & 7;
            int ch = mt * 16 + (l & 15), ci = ((l >> 4) << 3) + j;
            wsh[W3F_H + e3] = f2bf(w3[ch * 288 + ci * 9 + ks]);
        } else if (e < 23552 + 81920) {
            int ef = e - 23552;                          // [0, 81920)
            int mt = ef / 10240, r = ef % 10240;
            int ks = r >> 9, l = (r >> 3) & 63, j = ef & 7;
            int ch = mt * 16 + (l & 15);
            int kp = ks * 32 + ((l >> 4) << 3) + j;      // k' in [0,640)
            int w  = kp / 160, lk = kp - w * 160;
            float v = 0.f;
            if (lk < 144) v = wfc1[ch * 576 + (w * 16 + lk / 9) * 9 + (lk % 9)];
            wsh[WFC1F_H + ef] = f2bf(v);
        } else {
            int e4 = e - 105472;                         // [0, 1024)
            int half = e4 >> 9, l = (e4 >> 3) & 63, j = e4 & 7;
            int g = l >> 4, ch = l & 15;
            float w = 0.f;
            if (g < 3 && !(j & 1) && (j >> 1) < 3)
                w = (float)y_int[ch * 9 + g * 3 + (j >> 1)];
            unsigned short hib = f2bf(w);
            if (half == 0) {
                wsh[W1F_H + e4] = hib;
            } else {
                float hif = __builtin_bit_cast(float, (unsigned int)hib << 16);
                wsh[W1F_H + e4] = f2bf(w - hif);         // exact residual
            }
        }
    }
}

// 1 image per block (256 thr, 4 waves), 1024 blocks, FOUR barriers.
// Phase A: stage pixels as dup-bf16 dwords PX4[30][40] + zero all borders.
// Phase B: conv1 via MFMA (hi/lo exact split).  Phase C: conv2 (MFMA).
// Phase D: conv3 (MFMA) -> FLAT k'-region -> FC1 partial (no barrier).
// Phase E: FC2 combine.
// LDS: PX4 4800B + F1 8192B + F2 5184B = 18176B. FLAT/Hp alias F1.
__global__ __launch_bounds__(256, 4) void fused_cnn(
    const int* __restrict__ x_img,
    const float* __restrict__ ws,
    const float* __restrict__ bfc1,
    const float* __restrict__ wfc2, const float* __restrict__ bfc2,
    float* __restrict__ out)
{
    const int tid  = threadIdx.x;
    const int lane = tid & 63;
    const int wv   = __builtin_amdgcn_readfirstlane(tid >> 6);  // 0..3
    const int img  = blockIdx.x;
    const unsigned short* wsh = (const unsigned short*)ws;

    __shared__ __align__(16) char         s_f1[8192];
    __shared__ __align__(16) char         s_f2[5184];
    __shared__ __align__(16) unsigned int s_px[1200];   // [30 rows][40 dwords]
    ushort_t* FLAT = (ushort_t*)s_f1;             // 640 bf16 (F1 dead after conv2)
    float*    Hp   = (float*)(s_f1 + 1536);       // [4][128] f32

    // ---- phase A: stage pixels (dup-bf16 dwords) + zero borders ----
    const int* xp = x_img + img * 784;
    for (int i = tid; i < 784; i += 256) {
        int r = i / 28, c = i - r * 28;
        float f = (float)xp[i];
        unsigned int b = __builtin_bit_cast(unsigned int, f) >> 16;
        s_px[(r + 1) * 40 + c + 1] = b | (b << 16);
    }
    {
        uint4 z = make_uint4(0u, 0u, 0u, 0u);
        if (tid < 28) {                    // PX side borders, row tid+1
            unsigned int* row = s_px + (tid + 1) * 40;
            row[0] = 0u;
            #pragma unroll
            for (int c = 29; c < 40; c++) row[c] = 0u;
        } else if (tid < 48) {             // PX rows 0, 29
            int j = tid - 28;              // 0..19
            int row = (j < 10) ? 0 : 29, ch = (j < 10) ? j : j - 10;
            *(uint4*)((char*)s_px + row * 160 + ch * 16) = z;
        } else if (tid < 168) {            // F1 borders (120 jobs)
            int zz = tid - 48;
            int c0 = zz / 60, b = zz % 60, pos;
            if (b < 16)      pos = b;
            else if (b < 32) pos = 240 + (b - 16);
            else if (b < 46) pos = (b - 31) * 16;
            else             pos = (b - 45) * 16 + 15;
            *(uint4*)(s_f1 + c0 * 4096 + pos * 16) = z;
        } else {                           // F2 borders (128 jobs / 88 thr)
            int i0 = tid - 168;
            #pragma unroll
            for (int rep = 0; rep < 2; rep++) {
                int i2 = i0 + rep * 88;
                if (i2 < 128) {
                    int q = i2 >> 5, b = i2 & 31, pos;
                    if (b < 9)       pos = b;
                    else if (b < 18) pos = 72 + (b - 9);
                    else if (b < 25) pos = (b - 17) * 9;
                    else             pos = (b - 24) * 9 + 8;
                    *(uint4*)(s_f2 + q * 1296 + pos * 16) = z;
                }
            }
        }
    }
    __syncthreads();   // bar 1: PX + borders ready

    // ---- phase B: conv1 via MFMA (hi/lo exact) -> F1 ----
    {
        bf16x8 A1H = *(const bf16x8*)(const void*)(wsh + W1F_H + lane * 8);
        bf16x8 A1L = *(const bf16x8*)(const void*)(wsh + W1F_H + (64 + lane) * 8);
        const int n = lane & 15, g = lane >> 4;
        const int gp = (g < 2) ? g : 2;
        float a1v[4], c1v[4];
        #pragma unroll
        for (int r = 0; r < 4; r++) {
            int ch = g * 4 + r;
            a1v[r] = ws[CST_OFF + ch];
            c1v[r] = ws[CST_OFF + 16 + ch];
        }
        for (int p1 = wv; p1 < 14; p1 += 4) {
            const unsigned int* rb = s_px + (2 * p1 + gp) * 40 + n;
            #pragma unroll
            for (int xt = 0; xt < 2; xt++) {
                const unsigned int* r0 = rb + xt * 16;
                u32x4 t0 = {r0[0], r0[1], r0[2], r0[3]};
                u32x4 t1 = {r0[40], r0[41], r0[42], r0[43]};
                bf16x8 B0 = __builtin_bit_cast(bf16x8, t0);   // y = 2p1
                bf16x8 B1 = __builtin_bit_cast(bf16x8, t1);   // y = 2p1+1
                f32x4 aA = {0.f, 0.f, 0.f, 0.f}, aB = {0.f, 0.f, 0.f, 0.f};
                aA = MFMA16(A1L, B0, aA); aA = MFMA16(A1H, B0, aA);
                aB = MFMA16(A1L, B1, aB); aB = MFMA16(A1H, B1, aB);
                float hp[4];
                #pragma unroll
                for (int r = 0; r < 4; r++) {
                    float vp = fmaxf(aA[r], aB[r]);
                    hp[r] = fmaxf(vp, __shfl_xor(vp, 1));
                }
                if (!(n & 1) && (xt == 0 || n < 12)) {
                    int xpo = xt * 8 + (n >> 1);
                    int pos = (p1 + 1) * 16 + (xpo + 1);
                    int ch0 = g * 4;
                    unsigned int lo = (unsigned int)f2bf(fmaxf(hp[0] * a1v[0] + c1v[0], 0.f)) |
                                      ((unsigned int)f2bf(fmaxf(hp[1] * a1v[1] + c1v[1], 0.f)) << 16);
                    unsigned int hi = (unsigned int)f2bf(fmaxf(hp[2] * a1v[2] + c1v[2], 0.f)) |
                                      ((unsigned int)f2bf(fmaxf(hp[3] * a1v[3] + c1v[3], 0.f)) << 16);
                    *(uint2*)(s_f1 + (ch0 >> 3) * 4096 + pos * 16 + (ch0 & 7) * 2) = make_uint2(lo, hi);
                }
            }
        }
    }
    __syncthreads();   // bar 2: F1 ready

    // ---- phase C: conv2 via MFMA, rows p in {wv, wv+4} ----
    {
        const int x = lane & 15, g = lane >> 4;
        const int tapb = g >> 1, c0 = g & 1;
        bf16x8 A2[2][5];
        #pragma unroll
        for (int m = 0; m < 2; m++)
            #pragma unroll
            for (int s = 0; s < 5; s++)
                A2[m][s] = *(const bf16x8*)(const void*)(wsh + W2F_H + ((m * 5 + s) * 64 + lane) * 8);
        int voff[5];
        #pragma unroll
        for (int s = 0; s < 5; s++) {
            int tap = 2 * s + tapb;
            int dy = (tap < 9) ? tap / 3 : 0, dx = (tap < 9) ? tap % 3 : 0;
            voff[s] = c0 * 4096 + (dy * 16 + x + dx) * 16;
        }
        float a2v[2][4], c2v[2][4];
        #pragma unroll
        for (int m = 0; m < 2; m++)
            #pragma unroll
            for (int r = 0; r < 4; r++) {
                int ch = m * 16 + g * 4 + r;
                a2v[m][r] = ws[CST_OFF + 32 + ch];
                c2v[m][r] = ws[CST_OFF + 64 + ch];
            }
        for (int p = wv; p < 7; p += 4) {
            const char* bp = s_f1 + p * 512;
            bf16x8 B0[5], B1[5];
            #pragma unroll
            for (int s = 0; s < 5; s++) {
                B0[s] = *(const bf16x8*)(const void*)(bp + voff[s]);
                B1[s] = *(const bf16x8*)(const void*)(bp + 256 + voff[s]);
            }
            #pragma unroll
            for (int m = 0; m < 2; m++) {
                f32x4 a0 = {0.f, 0.f, 0.f, 0.f}, a1 = {0.f, 0.f, 0.f, 0.f};
                #pragma unroll
                for (int s = 0; s < 5; s++) {
                    a0 = MFMA16(A2[m][s], B0[s], a0);
                    a1 = MFMA16(A2[m][s], B1[s], a1);
                }
                float hp[4];
                #pragma unroll
                for (int r = 0; r < 4; r++) {
                    float vp = fmaxf(a0[r], a1[r]);
                    hp[r] = fmaxf(vp, __shfl_xor(vp, 1));
                }
                if (!(x & 1) && x < 14) {
                    int xp2 = x >> 1;
                    int pp  = (p + 1) * 9 + xp2 + 1;
                    int ch0 = m * 16 + g * 4;
                    unsigned int lo = (unsigned int)f2bf(fmaxf(hp[0] * a2v[m][0] + c2v[m][0], 0.f)) |
                                      ((unsigned int)f2bf(fmaxf(hp[1] * a2v[m][1] + c2v[m][1], 0.f)) << 16);
                    unsigned int hi = (unsigned int)f2bf(fmaxf(hp[2] * a2v[m][2] + c2v[m][2], 0.f)) |
                                      ((unsigned int)f2bf(fmaxf(hp[3] * a2v[m][3] + c2v[m][3], 0.f)) << 16);
                    *(uint2*)(s_f2 + (ch0 >> 3) * 1296 + pp * 16 + (ch0 & 7) * 2) = make_uint2(lo, hi);
                }
            }
        }
    }
    __syncthreads();   // bar 3: F2 ready (F1 dead -> FLAT/Hp scratch)

    // ---- phase D: conv3 (mt = wv) -> FLAT[wv*160..] -> FC1 partial ----
    {
        const int mt = wv;
        bf16x8 A3[9];
        #pragma unroll
        for (int ks = 0; ks < 9; ks++)
            A3[ks] = *(const bf16x8*)(const void*)(wsh + W3F_H + ((mt * 9 + ks) * 64 + lane) * 8);
        const int x8 = lane & 7, ry = (lane >> 3) & 1, qg = lane >> 4;
        int voff3[9];
        #pragma unroll
        for (int ks = 0; ks < 9; ks++) {
            int dy = ks / 3, dx = ks % 3;
            voff3[ks] = qg * 1296 + ((ry + dy) * 9 + x8 + dx) * 16;
        }
        float a3v[4], c3v[4];
        #pragma unroll
        for (int r = 0; r < 4; r++) {
            int ch = mt * 16 + qg * 4 + r;
            a3v[r] = ws[CST_OFF + 96 + ch];
            c3v[r] = ws[CST_OFF + 160 + ch];
        }
        if (lane < 16) FLAT[wv * 160 + 144 + lane] = 0;
        #pragma unroll
        for (int t = 0; t < 3; t++) {
            bf16x8 bb[9];
            #pragma unroll
            for (int ks = 0; ks < 9; ks++)
                bb[ks] = *(const bf16x8*)(const void*)(s_f2 + t * 288 + voff3[ks]);
            f32x4 acc = {0.f, 0.f, 0.f, 0.f};
            #pragma unroll
            for (int ks = 0; ks < 9; ks++)
                acc = MFMA16(A3[ks], bb[ks], acc);
            float hp[4];
            #pragma unroll
            for (int r = 0; r < 4; r++) {
                float vp = fmaxf(acc[r], __shfl_xor(acc[r], 8));
                hp[r] = fmaxf(vp, __shfl_xor(vp, 1));
            }
            if (ry == 0 && !(x8 & 1) && x8 < 6) {
                int xp3 = x8 >> 1;
                #pragma unroll
                for (int r = 0; r < 4; r++) {
                    float v = fmaxf(hp[r] * a3v[r] + c3v[r], 0.f);
                    FLAT[wv * 160 + (qg * 4 + r) * 9 + t * 3 + xp3] = f2bf(v);
                }
            }
        }

        // FC1 partial: own k'-slices ks = 5wv..5wv+4, all 8 mt (B hoisted)
        const int g = lane >> 4;
        bf16x8 BV[5];
        #pragma unroll
        for (int ksl = 0; ksl < 5; ksl++)
            BV[ksl] = *(const bf16x8*)(const void*)(FLAT + (wv * 5 + ksl) * 32 + g * 8);
        #pragma unroll
        for (int mtf = 0; mtf < 8; mtf++) {
            f32x4 acc = {0.f, 0.f, 0.f, 0.f};
            #pragma unroll
            for (int ksl = 0; ksl < 5; ksl++) {
                int ks = wv * 5 + ksl;
                bf16x8 a = *(const bf16x8*)(const void*)(wsh + WFC1F_H + ((mtf * 20 + ks) * 64 + lane) * 8);
                acc = MFMA16(a, BV[ksl], acc);
            }
            if ((lane & 15) == 0) {
                int ch0 = mtf * 16 + g * 4;
                #pragma unroll
                for (int r = 0; r < 4; r++)
                    Hp[wv * 128 + ch0 + r] = acc[r];
            }
        }
    }
    __syncthreads();   // bar 4: Hp ready

    // ---- phase E: FC2, combine 4 partials ----
    if (tid < 160) {
        int o = tid / 16, l = tid & 15;
        float a = 0.f;
        #pragma unroll
        for (int k = l; k < 128; k += 16) {
            float h = Hp[k] + Hp[128 + k] + Hp[256 + k] + Hp[384 + k] + bfc1[k];
            h = fmaxf(h, 0.f);
            a += h * wfc2[o * 128 + k];
        }
        a += __shfl_xor(a, 8);
        a += __shfl_xor(a, 4);
        a += __shfl_xor(a, 2);
        a += __shfl_xor(a, 1);
        if (l == 0) out[img * 10 + o] = a + bfc2[o];
    }
}

extern "C" void kernel_launch(void* const* d_in, const int* in_sizes, int n_in,
                              void* d_out, int out_size, void* d_ws, size_t ws_size,
                              hipStream_t stream) {
    float* ws = (float*)d_ws;
    prep_kernel<<<(PREP_ITEMS + 255) / 256, 256, 0, stream>>>(
        (const int*)d_in[1],                        // y_int
        (const float*)d_in[15],                     // w2
        (const float*)d_in[17],                     // w3
        (const float*)d_in[19],                     // w_fc1
        (const float*)d_in[2],                      // bias1
        (const float*)d_in[3], (const float*)d_in[4], (const float*)d_in[5], (const float*)d_in[6],
        (const float*)d_in[7], (const float*)d_in[8], (const float*)d_in[9], (const float*)d_in[10],
        (const float*)d_in[16],                     // bias2
        (const float*)d_in[11], (const float*)d_in[12], (const float*)d_in[13], (const float*)d_in[14],
        (const float*)d_in[18],                     // bias3
        ws);
    fused_cnn<<<1024, 256, 0, stream>>>(
        (const int*)d_in[0],                        // x_img
        ws,
        (const float*)d_in[20],                     // b_fc1
        (const float*)d_in[21], (const float*)d_in[22],  // w_fc2, b_fc2
        (float*)d_out);
}